// Round 1
// baseline (42943.069 us; speedup 1.0000x reference)
//
#include <hip/hip_runtime.h>
#include <math.h>

#define D 768
#define NL 12
#define NH 12
#define HD 64
#define FF 3072
#define SEQ 512
#define BATCH 8
#define BT (BATCH*SEQ)
#define LN_EPS 1e-12f
#define MET_EPS 1e-6f

// ---------------- embedding + layernorm ----------------
__global__ __launch_bounds__(256) void embed_ln_kernel(
    const int* __restrict__ ids, const int* __restrict__ tt,
    const float* __restrict__ wemb, const float* __restrict__ pemb,
    const float* __restrict__ temb, const float* __restrict__ lnw,
    const float* __restrict__ lnb, float* __restrict__ h)
{
    int token = blockIdx.x;        // 0..BT-1
    int s = token % SEQ;
    int tid = threadIdx.x;
    int id = ids[token];
    int tv = tt[token];
    float x[3];
    float sum = 0.f, sq = 0.f;
#pragma unroll
    for (int i = 0; i < 3; i++) {
        int d = tid + i * 256;
        float v = wemb[(size_t)id * D + d] + pemb[(size_t)s * D + d] + temb[(size_t)tv * D + d];
        x[i] = v; sum += v; sq += v * v;
    }
    __shared__ float r1[256], r2[256];
    r1[tid] = sum; r2[tid] = sq; __syncthreads();
    for (int o = 128; o > 0; o >>= 1) {
        if (tid < o) { r1[tid] += r1[tid + o]; r2[tid] += r2[tid + o]; }
        __syncthreads();
    }
    float m = r1[0] / (float)D;
    float var = fmaxf(r2[0] / (float)D - m * m, 0.f);
    float inv = rsqrtf(var + LN_EPS);
#pragma unroll
    for (int i = 0; i < 3; i++) {
        int d = tid + i * 256;
        h[(size_t)token * D + d] = (x[i] - m) * inv * lnw[d] + lnb[d];
    }
}

// ---------------- residual + layernorm ----------------
__global__ __launch_bounds__(256) void ln_residual_kernel(
    const float* __restrict__ x, const float* __restrict__ res,
    const float* __restrict__ w, const float* __restrict__ bb,
    float* __restrict__ out)
{
    int token = blockIdx.x;
    int tid = threadIdx.x;
    float v[3];
    float sum = 0.f, sq = 0.f;
#pragma unroll
    for (int i = 0; i < 3; i++) {
        int d = tid + i * 256;
        float t = x[(size_t)token * D + d] + res[(size_t)token * D + d];
        v[i] = t; sum += t; sq += t * t;
    }
    __shared__ float r1[256], r2[256];
    r1[tid] = sum; r2[tid] = sq; __syncthreads();
    for (int o = 128; o > 0; o >>= 1) {
        if (tid < o) { r1[tid] += r1[tid + o]; r2[tid] += r2[tid + o]; }
        __syncthreads();
    }
    float m = r1[0] / (float)D;
    float var = fmaxf(r2[0] / (float)D - m * m, 0.f);
    float inv = rsqrtf(var + LN_EPS);
#pragma unroll
    for (int i = 0; i < 3; i++) {
        int d = tid + i * 256;
        out[(size_t)token * D + d] = (v[i] - m) * inv * w[d] + bb[d];
    }
}

// ---------------- fp32 tiled GEMM: out = X(MxK) @ W(KxN) + bias, opt GELU ----------------
#define GBM 64
#define GBN 64
#define GBK 16
__global__ __launch_bounds__(256) void gemm_kernel(
    const float* __restrict__ X, const float* __restrict__ W,
    const float* __restrict__ bias, float* __restrict__ out,
    int M, int N, int K, int act)
{
    __shared__ float As[GBK][GBM + 1];
    __shared__ float Bs[GBK][GBN + 1];
    int tid = threadIdx.x;
    int tx = tid & 15, ty = tid >> 4;
    int row0 = blockIdx.y * GBM, col0 = blockIdx.x * GBN;
    float acc[4][4] = {};
    const int a_kk = tid & 15;   // k within tile
    const int a_r0 = tid >> 4;   // 0..15 step 16
    const int b_c = tid & 63;
    const int b_k0 = tid >> 6;   // 0..3 step 4

    for (int k0 = 0; k0 < K; k0 += GBK) {
#pragma unroll
        for (int r = a_r0; r < GBM; r += 16)
            As[a_kk][r] = X[(size_t)(row0 + r) * K + k0 + a_kk];
#pragma unroll
        for (int kk2 = b_k0; kk2 < GBK; kk2 += 4)
            Bs[kk2][b_c] = W[(size_t)(k0 + kk2) * N + col0 + b_c];
        __syncthreads();
#pragma unroll
        for (int kk2 = 0; kk2 < GBK; ++kk2) {
            float av[4], bv[4];
#pragma unroll
            for (int i = 0; i < 4; i++) av[i] = As[kk2][ty * 4 + i];
#pragma unroll
            for (int j = 0; j < 4; j++) bv[j] = Bs[kk2][tx * 4 + j];
#pragma unroll
            for (int i = 0; i < 4; i++)
#pragma unroll
                for (int j = 0; j < 4; j++)
                    acc[i][j] += av[i] * bv[j];
        }
        __syncthreads();
    }
#pragma unroll
    for (int i = 0; i < 4; i++) {
        int rr = row0 + ty * 4 + i;
#pragma unroll
        for (int j = 0; j < 4; j++) {
            int cc = col0 + tx * 4 + j;
            float v = acc[i][j] + bias[cc];
            if (act == 1) v = 0.5f * v * (1.f + erff(v * 0.70710678118654752f));
            out[(size_t)rr * N + cc] = v;
        }
    }
}

// ---------------- mean pool over sequence ----------------
__global__ void meanpool_kernel(const float* __restrict__ h, float* __restrict__ hbar)
{
    int d = blockIdx.x * blockDim.x + threadIdx.x;  // 0..D-1
    int b = blockIdx.y;
    float s = 0.f;
    const float* p = h + (size_t)b * SEQ * D + d;
    for (int i = 0; i < SEQ; i++) s += p[(size_t)i * D];
    hbar[b * D + d] = s * (1.0f / SEQ);
}

// ---------------- context projection -> sigmoid weights (first HD cols only) ----------------
__global__ __launch_bounds__(64) void ctxproj_kernel(
    const float* __restrict__ hbar, const float* __restrict__ Wcp,
    const float* __restrict__ bcp, float* __restrict__ cw)
{
    int b = blockIdx.x;
    int i = threadIdx.x;       // 0..63
    float s = bcp[i];
    const float* hb = hbar + (size_t)b * D;
    for (int dd = 0; dd < D; ++dd) s += hb[dd] * Wcp[(size_t)dd * D + i];
    cw[b * HD + i] = 1.f / (1.f + expf(-s));
}

// ---------------- metric build + Gauss-Jordan inverse (per batch) ----------------
__global__ __launch_bounds__(256) void metric_inv_kernel(
    const float* __restrict__ Lm, const float* __restrict__ dg,
    const float* __restrict__ cw, float* __restrict__ ginv)
{
    int b = blockIdx.x;
    int tid = threadIdx.x;
    __shared__ float lmod[HD][HD];        // 16 KB
    __shared__ float AI[HD][2 * HD + 1];  // ~33 KB
    __shared__ float fvec[HD];
    __shared__ float pivinv_s;

    for (int idx = tid; idx < HD * HD; idx += 256) {
        int i = idx >> 6, j = idx & 63;
        lmod[i][j] = Lm[i * 64 + j] * cw[b * HD + i];   // Lm row stride R=64
    }
    __syncthreads();
    for (int idx = tid; idx < HD * HD; idx += 256) {
        int i = idx >> 6, j = idx & 63;
        float s = 0.f;
        for (int t = 0; t < HD; t++) s += lmod[i][t] * lmod[j][t];
        if (i == j) s += dg[i] + MET_EPS + 0.1f;
        AI[i][j] = s;
        AI[i][HD + j] = (i == j) ? 1.f : 0.f;
    }
    __syncthreads();
    for (int k = 0; k < HD; k++) {
        if (tid == 0) pivinv_s = 1.f / AI[k][k];
        __syncthreads();
        float pv = pivinv_s;
        if (tid < 2 * HD) AI[k][tid] *= pv;
        __syncthreads();
        if (tid < HD) fvec[tid] = AI[tid][k];
        __syncthreads();
        for (int idx = tid; idx < HD * 2 * HD; idx += 256) {
            int i = idx >> 7, j = idx & 127;
            if (i != k) AI[i][j] -= fvec[i] * AI[k][j];
        }
        __syncthreads();
    }
    for (int idx = tid; idx < HD * HD; idx += 256) {
        int i = idx >> 6, j = idx & 63;
        ginv[((size_t)b * HD + i) * HD + j] = AI[i][HD + j];
    }
}

// ---------------- q <- q @ g_inv (in place, per token/head) ----------------
__global__ __launch_bounds__(64) void qg_kernel(
    float* __restrict__ q, const float* __restrict__ ginv)
{
    int token = blockIdx.x;
    int h = blockIdx.y;
    int b = token / SEQ;
    int e = threadIdx.x;
    __shared__ float qrow[HD];
    float* qp = q + (size_t)token * D + h * HD;
    qrow[e] = qp[e];
    __syncthreads();
    const float* g = ginv + (size_t)b * HD * HD;
    float s = 0.f;
#pragma unroll
    for (int d2 = 0; d2 < HD; ++d2) s += qrow[d2] * g[d2 * HD + e];
    qp[e] = s;
}

// ---------------- attention: one block per (b,h,q-row), fused softmax ----------------
__global__ __launch_bounds__(128) void attn_kernel(
    const float* __restrict__ qg, const float* __restrict__ kmat,
    const float* __restrict__ vmat, float* __restrict__ ctx)
{
    int qpos = blockIdx.x, h = blockIdx.y, b = blockIdx.z;
    int tid = threadIdx.x;
    __shared__ float qrow[HD];
    __shared__ float probs[SEQ];
    __shared__ float red[128];
    const size_t qoff = ((size_t)(b * SEQ + qpos)) * D + h * HD;
    if (tid < HD) qrow[tid] = qg[qoff + tid];
    __syncthreads();
    for (int kp = tid; kp < SEQ; kp += 128) {
        const float* kr = kmat + ((size_t)(b * SEQ + kp)) * D + h * HD;
        float s = 0.f;
#pragma unroll
        for (int d2 = 0; d2 < HD; ++d2) s += qrow[d2] * kr[d2];
        probs[kp] = s * 0.125f;   // 1/sqrt(64)
    }
    __syncthreads();
    float lm = -1e30f;
    for (int kp = tid; kp < SEQ; kp += 128) lm = fmaxf(lm, probs[kp]);
    red[tid] = lm; __syncthreads();
    for (int o = 64; o > 0; o >>= 1) {
        if (tid < o) red[tid] = fmaxf(red[tid], red[tid + o]);
        __syncthreads();
    }
    float mx = red[0];
    __syncthreads();
    float ls = 0.f;
    for (int kp = tid; kp < SEQ; kp += 128) {
        float p = expf(probs[kp] - mx);
        probs[kp] = p; ls += p;
    }
    red[tid] = ls; __syncthreads();
    for (int o = 64; o > 0; o >>= 1) {
        if (tid < o) red[tid] += red[tid + o];
        __syncthreads();
    }
    float inv = 1.f / red[0];
    __syncthreads();
    int d2 = tid & 63;
    int k0 = (tid >> 6) * 256;
    float acc = 0.f;
    for (int kp = k0; kp < k0 + 256; ++kp)
        acc += probs[kp] * vmat[((size_t)(b * SEQ + kp)) * D + h * HD + d2];
    red[tid] = acc; __syncthreads();
    if (tid < HD)
        ctx[qoff + tid] = (red[tid] + red[tid + 64]) * inv;
}

// ---------------- host ----------------
extern "C" void kernel_launch(void* const* d_in, const int* in_sizes, int n_in,
                              void* d_out, int out_size, void* d_ws, size_t ws_size,
                              hipStream_t stream)
{
    (void)in_sizes; (void)n_in; (void)out_size; (void)ws_size;
    const int*   input_ids  = (const int*)d_in[0];
    const int*   token_type = (const int*)d_in[1];
    const float* word_emb   = (const float*)d_in[2];
    const float* pos_emb    = (const float*)d_in[3];
    const float* type_emb   = (const float*)d_in[4];
    const float* ln_emb_w   = (const float*)d_in[5];
    const float* ln_emb_b   = (const float*)d_in[6];
    const float* Wq = (const float*)d_in[7];
    const float* bq = (const float*)d_in[8];
    const float* Wk = (const float*)d_in[9];
    const float* bk = (const float*)d_in[10];
    const float* Wv = (const float*)d_in[11];
    const float* bv = (const float*)d_in[12];
    const float* Lm = (const float*)d_in[13];
    const float* dg = (const float*)d_in[14];
    const float* Wcp = (const float*)d_in[15];
    const float* bcp = (const float*)d_in[16];
    const float* Wi = (const float*)d_in[17];
    const float* bi = (const float*)d_in[18];
    const float* Wo = (const float*)d_in[19];
    const float* bo = (const float*)d_in[20];
    const float* ln1w = (const float*)d_in[21];
    const float* ln1b = (const float*)d_in[22];
    const float* ln2w = (const float*)d_in[23];
    const float* ln2b = (const float*)d_in[24];

    float* h = (float*)d_out;          // persistent hidden state, final value IS the output
    float* ws = (float*)d_ws;
    size_t off = 0;
    float* q    = ws + off; off += (size_t)BT * D;
    float* kbuf = ws + off; off += (size_t)BT * D;
    float* vbuf = ws + off; off += (size_t)BT * D;
    float* ctx  = ws + off; off += (size_t)BT * D;
    float* a    = ws + off; off += (size_t)BT * D;
    float* f    = ws + off; off += (size_t)BT * FF;
    float* hbar = ws + off; off += (size_t)BATCH * D;
    float* cw   = ws + off; off += (size_t)BATCH * HD;
    float* ginv = ws + off; off += (size_t)BATCH * HD * HD;
    float* obuf = vbuf;                // v is dead after attention; reuse

    embed_ln_kernel<<<BT, 256, 0, stream>>>(input_ids, token_type, word_emb, pos_emb,
                                            type_emb, ln_emb_w, ln_emb_b, h);

    dim3 gQKV(D / GBN, BT / GBM);      // (12, 64)
    dim3 gFF1(FF / GBN, BT / GBM);     // (48, 64)
    dim3 gFF2(D / GBN, BT / GBM);      // (12, 64)

    for (int l = 0; l < NL; ++l) {
        const float* Wq_l = Wq + (size_t)l * D * D;
        const float* bq_l = bq + (size_t)l * D;
        const float* Wk_l = Wk + (size_t)l * D * D;
        const float* bk_l = bk + (size_t)l * D;
        const float* Wv_l = Wv + (size_t)l * D * D;
        const float* bv_l = bv + (size_t)l * D;
        const float* Lm_l = Lm + (size_t)l * D * 64;
        const float* dg_l = dg + (size_t)l * D;
        const float* Wcp_l = Wcp + (size_t)l * D * D;
        const float* bcp_l = bcp + (size_t)l * D;
        const float* Wi_l = Wi + (size_t)l * D * FF;
        const float* bi_l = bi + (size_t)l * FF;
        const float* Wo_l = Wo + (size_t)l * FF * D;
        const float* bo_l = bo + (size_t)l * D;
        const float* ln1w_l = ln1w + (size_t)l * D;
        const float* ln1b_l = ln1b + (size_t)l * D;
        const float* ln2w_l = ln2w + (size_t)l * D;
        const float* ln2b_l = ln2b + (size_t)l * D;

        gemm_kernel<<<gQKV, 256, 0, stream>>>(h, Wq_l, bq_l, q,    BT, D, D, 0);
        gemm_kernel<<<gQKV, 256, 0, stream>>>(h, Wk_l, bk_l, kbuf, BT, D, D, 0);
        gemm_kernel<<<gQKV, 256, 0, stream>>>(h, Wv_l, bv_l, vbuf, BT, D, D, 0);

        meanpool_kernel<<<dim3(D / 256, BATCH), 256, 0, stream>>>(h, hbar);
        ctxproj_kernel<<<BATCH, 64, 0, stream>>>(hbar, Wcp_l, bcp_l, cw);
        metric_inv_kernel<<<BATCH, 256, 0, stream>>>(Lm_l, dg_l, cw, ginv);
        qg_kernel<<<dim3(BT, NH), 64, 0, stream>>>(q, ginv);

        attn_kernel<<<dim3(SEQ, NH, BATCH), 128, 0, stream>>>(q, kbuf, vbuf, ctx);

        ln_residual_kernel<<<BT, 256, 0, stream>>>(ctx, h, ln1w_l, ln1b_l, a);

        gemm_kernel<<<gFF1, 256, 0, stream>>>(a, Wi_l, bi_l, f, BT, FF, D, 1);
        gemm_kernel<<<gFF2, 256, 0, stream>>>(f, Wo_l, bo_l, obuf, BT, D, FF, 0);

        ln_residual_kernel<<<BT, 256, 0, stream>>>(obuf, a, ln2w_l, ln2b_l, h);
    }
}

// Round 2
// 9435.714 us; speedup vs baseline: 4.5511x; 4.5511x over previous
//
#include <hip/hip_runtime.h>
#include <math.h>

#define D 768
#define NL 12
#define NH 12
#define HD 64
#define FF 3072
#define SEQ 512
#define BATCH 8
#define BT (BATCH*SEQ)
#define LN_EPS 1e-12f
#define MET_EPS 1e-6f

typedef float f32x4 __attribute__((ext_vector_type(4)));
typedef __bf16 bf16x8 __attribute__((ext_vector_type(8)));
typedef short short8v __attribute__((ext_vector_type(8)));

__device__ __forceinline__ unsigned short f2b(float f) {
    unsigned u = __float_as_uint(f);
    u += 0x7fffu + ((u >> 16) & 1u);      // RNE
    return (unsigned short)(u >> 16);
}
__device__ __forceinline__ float b2f(unsigned short s) {
    return __uint_as_float(((unsigned)s) << 16);
}

// ---------------- embedding + layernorm (fp32 out + bf16 out) ----------------
__global__ __launch_bounds__(256) void embed_ln_kernel(
    const int* __restrict__ ids, const int* __restrict__ tt,
    const float* __restrict__ wemb, const float* __restrict__ pemb,
    const float* __restrict__ temb, const float* __restrict__ lnw,
    const float* __restrict__ lnb, float* __restrict__ h,
    unsigned short* __restrict__ hb)
{
    int token = blockIdx.x;
    int s = token % SEQ;
    int tid = threadIdx.x;
    int id = ids[token];
    int tv = tt[token];
    float x[3];
    float sum = 0.f, sq = 0.f;
#pragma unroll
    for (int i = 0; i < 3; i++) {
        int d = tid + i * 256;
        float v = wemb[(size_t)id * D + d] + pemb[(size_t)s * D + d] + temb[(size_t)tv * D + d];
        x[i] = v; sum += v; sq += v * v;
    }
    __shared__ float r1[256], r2[256];
    r1[tid] = sum; r2[tid] = sq; __syncthreads();
    for (int o = 128; o > 0; o >>= 1) {
        if (tid < o) { r1[tid] += r1[tid + o]; r2[tid] += r2[tid + o]; }
        __syncthreads();
    }
    float m = r1[0] / (float)D;
    float var = fmaxf(r2[0] / (float)D - m * m, 0.f);
    float inv = rsqrtf(var + LN_EPS);
#pragma unroll
    for (int i = 0; i < 3; i++) {
        int d = tid + i * 256;
        float v = (x[i] - m) * inv * lnw[d] + lnb[d];
        h[(size_t)token * D + d] = v;
        hb[(size_t)token * D + d] = f2b(v);
    }
}

// ---------------- residual + layernorm (fp32 out + bf16 out) ----------------
__global__ __launch_bounds__(256) void ln_residual_kernel(
    const float* __restrict__ x, const float* __restrict__ res,
    const float* __restrict__ w, const float* __restrict__ bb,
    float* __restrict__ out, unsigned short* __restrict__ outb)
{
    int token = blockIdx.x;
    int tid = threadIdx.x;
    float v[3];
    float sum = 0.f, sq = 0.f;
#pragma unroll
    for (int i = 0; i < 3; i++) {
        int d = tid + i * 256;
        float t = x[(size_t)token * D + d] + res[(size_t)token * D + d];
        v[i] = t; sum += t; sq += t * t;
    }
    __shared__ float r1[256], r2[256];
    r1[tid] = sum; r2[tid] = sq; __syncthreads();
    for (int o = 128; o > 0; o >>= 1) {
        if (tid < o) { r1[tid] += r1[tid + o]; r2[tid] += r2[tid + o]; }
        __syncthreads();
    }
    float m = r1[0] / (float)D;
    float var = fmaxf(r2[0] / (float)D - m * m, 0.f);
    float inv = rsqrtf(var + LN_EPS);
#pragma unroll
    for (int i = 0; i < 3; i++) {
        int d = tid + i * 256;
        float t = (v[i] - m) * inv * w[d] + bb[d];
        out[(size_t)token * D + d] = t;
        outb[(size_t)token * D + d] = f2b(t);
    }
}

// ---------------- transpose + fp32->bf16 convert: src K x N -> dst N x K ----------------
__global__ __launch_bounds__(256) void transpose_cvt_kernel(
    const float* __restrict__ src, unsigned short* __restrict__ dst, int K, int N)
{
    __shared__ float t[32][33];
    int tx = threadIdx.x & 31, ty = threadIdx.x >> 5;   // 32 x 8
    int kb = blockIdx.y * 32, nb = blockIdx.x * 32;
#pragma unroll
    for (int i = 0; i < 4; i++)
        t[ty + i * 8][tx] = src[(size_t)(kb + ty + i * 8) * N + nb + tx];
    __syncthreads();
#pragma unroll
    for (int i = 0; i < 4; i++)
        dst[(size_t)(nb + ty + i * 8) * K + kb + tx] = f2b(t[tx][ty + i * 8]);
}

// ---------------- bf16 MFMA GEMM: out = Xb(MxK) @ WTb(NxK)^T + bias ----------------
// 128x128 block tile, 4 waves each 64x64 (4x4 grid of 16x16x32 mfma)
__global__ __launch_bounds__(256) void gemm_bf16_kernel(
    const unsigned short* __restrict__ Xb, const unsigned short* __restrict__ WTb,
    const float* __restrict__ bias0, const float* __restrict__ bias1,
    const float* __restrict__ bias2, int seg,
    float* __restrict__ outF, unsigned short* __restrict__ outB,
    int M, int N, int K, int act)
{
    __shared__ unsigned short As[128][40];   // 32 k + 8 pad
    __shared__ unsigned short Bs[128][40];
    int tid = threadIdx.x;
    int wave = tid >> 6, lane = tid & 63;
    int wr = (wave >> 1) * 64, wc = (wave & 1) * 64;
    int row0 = blockIdx.y * 128, col0 = blockIdx.x * 128;
    int lm = lane & 15, lq = lane >> 4;
    f32x4 acc[4][4];
#pragma unroll
    for (int i = 0; i < 4; i++)
#pragma unroll
        for (int j = 0; j < 4; j++)
            acc[i][j] = (f32x4){0.f, 0.f, 0.f, 0.f};

    int srow = tid >> 2;          // 0..63
    int skq = (tid & 3) * 8;      // 0,8,16,24

    for (int k0 = 0; k0 < K; k0 += 32) {
        short8v a0 = *reinterpret_cast<const short8v*>(Xb + (size_t)(row0 + srow) * K + k0 + skq);
        short8v a1 = *reinterpret_cast<const short8v*>(Xb + (size_t)(row0 + srow + 64) * K + k0 + skq);
        short8v w0 = *reinterpret_cast<const short8v*>(WTb + (size_t)(col0 + srow) * K + k0 + skq);
        short8v w1 = *reinterpret_cast<const short8v*>(WTb + (size_t)(col0 + srow + 64) * K + k0 + skq);
        *reinterpret_cast<short8v*>(&As[srow][skq]) = a0;
        *reinterpret_cast<short8v*>(&As[srow + 64][skq]) = a1;
        *reinterpret_cast<short8v*>(&Bs[srow][skq]) = w0;
        *reinterpret_cast<short8v*>(&Bs[srow + 64][skq]) = w1;
        __syncthreads();
        bf16x8 af[4], bf[4];
#pragma unroll
        for (int t = 0; t < 4; t++) {
            af[t] = __builtin_bit_cast(bf16x8, *reinterpret_cast<const short8v*>(&As[wr + t * 16 + lm][lq * 8]));
            bf[t] = __builtin_bit_cast(bf16x8, *reinterpret_cast<const short8v*>(&Bs[wc + t * 16 + lm][lq * 8]));
        }
#pragma unroll
        for (int mt = 0; mt < 4; mt++)
#pragma unroll
            for (int nt = 0; nt < 4; nt++)
                acc[mt][nt] = __builtin_amdgcn_mfma_f32_16x16x32_bf16(af[mt], bf[nt], acc[mt][nt], 0, 0, 0);
        __syncthreads();
    }
#pragma unroll
    for (int mt = 0; mt < 4; mt++) {
#pragma unroll
        for (int nt = 0; nt < 4; nt++) {
            int col = col0 + wc + nt * 16 + lm;
            float bv = (col < seg) ? bias0[col] : ((col < 2 * seg) ? bias1[col - seg] : bias2[col - 2 * seg]);
#pragma unroll
            for (int r = 0; r < 4; r++) {
                int row = row0 + wr + mt * 16 + lq * 4 + r;
                float v = acc[mt][nt][r] + bv;
                if (act) v = 0.5f * v * (1.f + erff(v * 0.70710678118654752f));
                if (outF) outF[(size_t)row * N + col] = v;
                if (outB) outB[(size_t)row * N + col] = f2b(v);
            }
        }
    }
}

// ---------------- mean pool over sequence ----------------
__global__ void meanpool_kernel(const float* __restrict__ h, float* __restrict__ hbar)
{
    int d = blockIdx.x * blockDim.x + threadIdx.x;
    int b = blockIdx.y;
    float s = 0.f;
    const float* p = h + (size_t)b * SEQ * D + d;
    for (int i = 0; i < SEQ; i++) s += p[(size_t)i * D];
    hbar[b * D + d] = s * (1.0f / SEQ);
}

// ---------------- context projection -> sigmoid weights (first HD cols) ----------------
__global__ __launch_bounds__(64) void ctxproj_kernel(
    const float* __restrict__ hbar, const float* __restrict__ Wcp,
    const float* __restrict__ bcp, float* __restrict__ cw)
{
    int b = blockIdx.x;
    int i = threadIdx.x;
    float s = bcp[i];
    const float* hb = hbar + (size_t)b * D;
    for (int dd = 0; dd < D; ++dd) s += hb[dd] * Wcp[(size_t)dd * D + i];
    cw[b * HD + i] = 1.f / (1.f + expf(-s));
}

// ---------------- metric build + Gauss-Jordan inverse (per batch) ----------------
__global__ __launch_bounds__(256) void metric_inv_kernel(
    const float* __restrict__ Lm, const float* __restrict__ dg,
    const float* __restrict__ cw, float* __restrict__ ginv)
{
    int b = blockIdx.x;
    int tid = threadIdx.x;
    __shared__ float lmod[HD][HD];
    __shared__ float AI[HD][2 * HD + 1];
    __shared__ float fvec[HD];
    __shared__ float pivinv_s;

    for (int idx = tid; idx < HD * HD; idx += 256) {
        int i = idx >> 6, j = idx & 63;
        lmod[i][j] = Lm[i * 64 + j] * cw[b * HD + i];
    }
    __syncthreads();
    for (int idx = tid; idx < HD * HD; idx += 256) {
        int i = idx >> 6, j = idx & 63;
        float s = 0.f;
        for (int t = 0; t < HD; t++) s += lmod[i][t] * lmod[j][t];
        if (i == j) s += dg[i] + MET_EPS + 0.1f;
        AI[i][j] = s;
        AI[i][HD + j] = (i == j) ? 1.f : 0.f;
    }
    __syncthreads();
    for (int k = 0; k < HD; k++) {
        if (tid == 0) pivinv_s = 1.f / AI[k][k];
        __syncthreads();
        float pv = pivinv_s;
        if (tid < 2 * HD) AI[k][tid] *= pv;
        __syncthreads();
        if (tid < HD) fvec[tid] = AI[tid][k];
        __syncthreads();
        for (int idx = tid; idx < HD * 2 * HD; idx += 256) {
            int i = idx >> 7, j = idx & 127;
            if (i != k) AI[i][j] -= fvec[i] * AI[k][j];
        }
        __syncthreads();
    }
    for (int idx = tid; idx < HD * HD; idx += 256) {
        int i = idx >> 6, j = idx & 63;
        ginv[((size_t)b * HD + i) * HD + j] = AI[i][HD + j];
    }
}

// ---------------- q <- q @ g_inv, bf16 in place in qkvb ----------------
__global__ __launch_bounds__(64) void qg_kernel(
    unsigned short* __restrict__ qkvb, const float* __restrict__ ginv)
{
    int token = blockIdx.x;
    int hh = blockIdx.y;
    int b = token / SEQ;
    int e = threadIdx.x;
    unsigned short* qp = qkvb + (size_t)token * 2304 + hh * HD;
    float qv = b2f(qp[e]);
    const float* g = ginv + (size_t)b * HD * HD;
    float s = 0.f;
#pragma unroll
    for (int d2 = 0; d2 < HD; ++d2) s += __shfl(qv, d2) * g[d2 * HD + e];
    qp[e] = f2b(s);
}

// ---------------- attention: chunked online-softmax, block = (qtile64, head, batch) ----------------
#define ACH 128
__global__ __launch_bounds__(256) void attn2_kernel(
    const unsigned short* __restrict__ qkvb, float* __restrict__ ctx)
{
    int qt = blockIdx.x, hh = blockIdx.y, b = blockIdx.z;
    int tid = threadIdx.x, wave = tid >> 6, lane = tid & 63;
    __shared__ unsigned short KT[64][ACH + 2];   // [d][kp], row = 65 words -> conflict-free
    __shared__ unsigned short VT[64][ACH + 2];   // [e][kp]
    __shared__ float oaccL[4][16][64];
    __shared__ float mL[4][16], lL[4][16];
    __shared__ float qs[4][64];
    __shared__ float pr[4][ACH];

#pragma unroll
    for (int i = 0; i < 16; i++) oaccL[wave][i][lane] = 0.f;
    if (lane < 16) { mL[wave][lane] = -1e30f; lL[wave][lane] = 0.f; }

    const int tok0 = b * SEQ;
    const size_t kcol = 768 + (size_t)hh * HD;
    const size_t vcol = 1536 + (size_t)hh * HD;

    for (int c = 0; c < SEQ / ACH; c++) {
        __syncthreads();   // protect KT/VT from previous-iteration readers; orders init too
        int dq = (tid & 7) * 8;
        int kpb = tid >> 3;       // 0..31
#pragma unroll
        for (int it = 0; it < ACH / 32; it++) {
            int kpl = kpb + it * 32;
            int token = tok0 + c * ACH + kpl;
            short8v kv = *reinterpret_cast<const short8v*>(qkvb + (size_t)token * 2304 + kcol + dq);
            short8v vv = *reinterpret_cast<const short8v*>(qkvb + (size_t)token * 2304 + vcol + dq);
            const unsigned short* kel = (const unsigned short*)&kv;
            const unsigned short* vel = (const unsigned short*)&vv;
#pragma unroll
            for (int j = 0; j < 8; j++) {
                KT[dq + j][kpl] = kel[j];
                VT[dq + j][kpl] = vel[j];
            }
        }
        __syncthreads();

        for (int i = 0; i < 16; i++) {
            int row = qt * 64 + wave * 16 + i;
            float qv = b2f(qkvb[(size_t)(tok0 + row) * 2304 + hh * HD + lane]);
            qs[wave][lane] = qv;
            __builtin_amdgcn_wave_barrier();
            float s0 = 0.f, s1 = 0.f;
#pragma unroll
            for (int d4 = 0; d4 < 16; d4++) {
                float4 qq = *reinterpret_cast<const float4*>(&qs[wave][d4 * 4]);
#pragma unroll
                for (int jj = 0; jj < 4; jj++) {
                    int d = d4 * 4 + jj;
                    unsigned int kk = *reinterpret_cast<const unsigned int*>(&KT[d][2 * lane]);
                    float qd = (jj == 0) ? qq.x : (jj == 1) ? qq.y : (jj == 2) ? qq.z : qq.w;
                    s0 = fmaf(qd, __uint_as_float(kk << 16), s0);
                    s1 = fmaf(qd, __uint_as_float(kk & 0xffff0000u), s1);
                }
            }
            s0 *= 0.125f; s1 *= 0.125f;
            float sm = fmaxf(s0, s1);
#pragma unroll
            for (int off = 32; off; off >>= 1) sm = fmaxf(sm, __shfl_xor(sm, off));
            float mold = mL[wave][i];
            float mnew = fmaxf(mold, sm);
            float alpha = __expf(mold - mnew);
            float p0 = __expf(s0 - mnew), p1 = __expf(s1 - mnew);
            float ps = p0 + p1;
#pragma unroll
            for (int off = 32; off; off >>= 1) ps += __shfl_xor(ps, off);
            mL[wave][i] = mnew;
            lL[wave][i] = lL[wave][i] * alpha + ps;
            float2 p01; p01.x = p0; p01.y = p1;
            *reinterpret_cast<float2*>(&pr[wave][2 * lane]) = p01;
            __builtin_amdgcn_wave_barrier();
            float racc = 0.f;
#pragma unroll
            for (int j4 = 0; j4 < ACH / 4; j4++) {
                float4 pp = *reinterpret_cast<const float4*>(&pr[wave][j4 * 4]);
                unsigned int v0 = *reinterpret_cast<const unsigned int*>(&VT[lane][j4 * 4]);
                unsigned int v1 = *reinterpret_cast<const unsigned int*>(&VT[lane][j4 * 4 + 2]);
                racc = fmaf(pp.x, __uint_as_float(v0 << 16), racc);
                racc = fmaf(pp.y, __uint_as_float(v0 & 0xffff0000u), racc);
                racc = fmaf(pp.z, __uint_as_float(v1 << 16), racc);
                racc = fmaf(pp.w, __uint_as_float(v1 & 0xffff0000u), racc);
            }
            oaccL[wave][i][lane] = oaccL[wave][i][lane] * alpha + racc;
            __builtin_amdgcn_wave_barrier();
        }
    }
#pragma unroll
    for (int i = 0; i < 16; i++) {
        int row = qt * 64 + wave * 16 + i;
        float inv = 1.f / lL[wave][i];
        ctx[(size_t)(tok0 + row) * D + hh * HD + lane] = oaccL[wave][i][lane] * inv;
    }
}

// ---------------- host ----------------
extern "C" void kernel_launch(void* const* d_in, const int* in_sizes, int n_in,
                              void* d_out, int out_size, void* d_ws, size_t ws_size,
                              hipStream_t stream)
{
    (void)in_sizes; (void)n_in; (void)out_size; (void)ws_size;
    const int*   input_ids  = (const int*)d_in[0];
    const int*   token_type = (const int*)d_in[1];
    const float* word_emb   = (const float*)d_in[2];
    const float* pos_emb    = (const float*)d_in[3];
    const float* type_emb   = (const float*)d_in[4];
    const float* ln_emb_w   = (const float*)d_in[5];
    const float* ln_emb_b   = (const float*)d_in[6];
    const float* Wq = (const float*)d_in[7];
    const float* bq = (const float*)d_in[8];
    const float* Wk = (const float*)d_in[9];
    const float* bk = (const float*)d_in[10];
    const float* Wv = (const float*)d_in[11];
    const float* bv = (const float*)d_in[12];
    const float* Lm = (const float*)d_in[13];
    const float* dg = (const float*)d_in[14];
    const float* Wcp = (const float*)d_in[15];
    const float* bcp = (const float*)d_in[16];
    const float* Wi = (const float*)d_in[17];
    const float* bi = (const float*)d_in[18];
    const float* Wo = (const float*)d_in[19];
    const float* bo = (const float*)d_in[20];
    const float* ln1w = (const float*)d_in[21];
    const float* ln1b = (const float*)d_in[22];
    const float* ln2w = (const float*)d_in[23];
    const float* ln2b = (const float*)d_in[24];

    float* h = (float*)d_out;

    // workspace layout (bytes)
    char* wsb = (char*)d_ws;
    size_t off = 0;
    auto alloc = [&](size_t bytes) { void* p = wsb + off; off += (bytes + 255) & ~(size_t)255; return p; };
    unsigned short* qkvb = (unsigned short*)alloc((size_t)BT * 2304 * 2);
    float*          ctx  = (float*)alloc((size_t)BT * D * 4);          // also reused as FFN out
    float*          a    = (float*)alloc((size_t)BT * D * 4);
    unsigned short* hb   = (unsigned short*)alloc((size_t)BT * D * 2); // also reused as ab
    unsigned short* fb   = (unsigned short*)alloc((size_t)BT * FF * 2);
    unsigned short* WqkvT= (unsigned short*)alloc((size_t)2304 * 768 * 2);
    unsigned short* WiT  = (unsigned short*)alloc((size_t)3072 * 768 * 2);
    unsigned short* WoT  = (unsigned short*)alloc((size_t)768 * 3072 * 2);
    float*          hbar = (float*)alloc((size_t)BATCH * D * 4);
    float*          cw   = (float*)alloc((size_t)BATCH * HD * 4);
    float*          ginv = (float*)alloc((size_t)BATCH * HD * HD * 4);
    unsigned short* ab = hb;
    float* obuf = ctx;

    embed_ln_kernel<<<BT, 256, 0, stream>>>(input_ids, token_type, word_emb, pos_emb,
                                            type_emb, ln_emb_w, ln_emb_b, h, hb);

    for (int l = 0; l < NL; ++l) {
        const float* Wq_l = Wq + (size_t)l * D * D;
        const float* bq_l = bq + (size_t)l * D;
        const float* Wk_l = Wk + (size_t)l * D * D;
        const float* bk_l = bk + (size_t)l * D;
        const float* Wv_l = Wv + (size_t)l * D * D;
        const float* bv_l = bv + (size_t)l * D;
        const float* Lm_l = Lm + (size_t)l * D * 64;
        const float* dg_l = dg + (size_t)l * D;
        const float* Wcp_l = Wcp + (size_t)l * D * D;
        const float* bcp_l = bcp + (size_t)l * D;
        const float* Wi_l = Wi + (size_t)l * D * FF;
        const float* bi_l = bi + (size_t)l * FF;
        const float* Wo_l = Wo + (size_t)l * FF * D;
        const float* bo_l = bo + (size_t)l * D;
        const float* ln1w_l = ln1w + (size_t)l * D;
        const float* ln1b_l = ln1b + (size_t)l * D;
        const float* ln2w_l = ln2w + (size_t)l * D;
        const float* ln2b_l = ln2b + (size_t)l * D;

        // weight transposes (into small per-layer-reused buffers)
        transpose_cvt_kernel<<<dim3(24, 24), 256, 0, stream>>>(Wq_l, WqkvT,                 768, 768);
        transpose_cvt_kernel<<<dim3(24, 24), 256, 0, stream>>>(Wk_l, WqkvT + 768 * 768,     768, 768);
        transpose_cvt_kernel<<<dim3(24, 24), 256, 0, stream>>>(Wv_l, WqkvT + 2 * 768 * 768, 768, 768);
        transpose_cvt_kernel<<<dim3(96, 24), 256, 0, stream>>>(Wi_l, WiT, 768, 3072);
        transpose_cvt_kernel<<<dim3(24, 96), 256, 0, stream>>>(Wo_l, WoT, 3072, 768);

        // fused QKV GEMM -> bf16
        gemm_bf16_kernel<<<dim3(2304 / 128, BT / 128), 256, 0, stream>>>(
            hb, WqkvT, bq_l, bk_l, bv_l, 768, nullptr, qkvb, BT, 2304, 768, 0);

        meanpool_kernel<<<dim3(D / 256, BATCH), 256, 0, stream>>>(h, hbar);
        ctxproj_kernel<<<BATCH, 64, 0, stream>>>(hbar, Wcp_l, bcp_l, cw);
        metric_inv_kernel<<<BATCH, 256, 0, stream>>>(Lm_l, dg_l, cw, ginv);
        qg_kernel<<<dim3(BT, NH), 64, 0, stream>>>(qkvb, ginv);

        attn2_kernel<<<dim3(SEQ / 64, NH, BATCH), 256, 0, stream>>>(qkvb, ctx);

        ln_residual_kernel<<<BT, 256, 0, stream>>>(ctx, h, ln1w_l, ln1b_l, a, ab);

        gemm_bf16_kernel<<<dim3(FF / 128, BT / 128), 256, 0, stream>>>(
            ab, WiT, bi_l, bi_l, bi_l, FF, nullptr, fb, BT, FF, 768, 1);
        gemm_bf16_kernel<<<dim3(D / 128, BT / 128), 256, 0, stream>>>(
            fb, WoT, bo_l, bo_l, bo_l, D, obuf, nullptr, BT, D, FF, 0);

        ln_residual_kernel<<<BT, 256, 0, stream>>>(obuf, a, ln2w_l, ln2b_l, h, hb);
    }
}

// Round 3
// 5916.685 us; speedup vs baseline: 7.2580x; 1.5948x over previous
//
#include <hip/hip_runtime.h>
#include <math.h>

#define D 768
#define NL 12
#define NH 12
#define HD 64
#define FF 3072
#define SEQ 512
#define BATCH 8
#define BT (BATCH*SEQ)
#define LN_EPS 1e-12f
#define MET_EPS 1e-6f

typedef float f32x4 __attribute__((ext_vector_type(4)));
typedef __bf16 bf16x8 __attribute__((ext_vector_type(8)));
typedef short short8v __attribute__((ext_vector_type(8)));

__device__ __forceinline__ unsigned short f2b(float f) {
    unsigned u = __float_as_uint(f);
    u += 0x7fffu + ((u >> 16) & 1u);      // RNE
    return (unsigned short)(u >> 16);
}
__device__ __forceinline__ float b2f(unsigned short s) {
    return __uint_as_float(((unsigned)s) << 16);
}
__device__ __forceinline__ void gload16(const void* g, void* l) {
    __builtin_amdgcn_global_load_lds((const __attribute__((address_space(1))) unsigned int*)g,
                                     (__attribute__((address_space(3))) unsigned int*)l,
                                     16, 0, 0);
}

// ---------------- embedding + layernorm (fp32 out + bf16 out) ----------------
__global__ __launch_bounds__(256) void embed_ln_kernel(
    const int* __restrict__ ids, const int* __restrict__ tt,
    const float* __restrict__ wemb, const float* __restrict__ pemb,
    const float* __restrict__ temb, const float* __restrict__ lnw,
    const float* __restrict__ lnb, float* __restrict__ h,
    unsigned short* __restrict__ hb)
{
    int token = blockIdx.x;
    int s = token % SEQ;
    int tid = threadIdx.x;
    int id = ids[token];
    int tv = tt[token];
    float x[3];
    float sum = 0.f, sq = 0.f;
#pragma unroll
    for (int i = 0; i < 3; i++) {
        int d = tid + i * 256;
        float v = wemb[(size_t)id * D + d] + pemb[(size_t)s * D + d] + temb[(size_t)tv * D + d];
        x[i] = v; sum += v; sq += v * v;
    }
    __shared__ float r1[256], r2[256];
    r1[tid] = sum; r2[tid] = sq; __syncthreads();
    for (int o = 128; o > 0; o >>= 1) {
        if (tid < o) { r1[tid] += r1[tid + o]; r2[tid] += r2[tid + o]; }
        __syncthreads();
    }
    float m = r1[0] / (float)D;
    float var = fmaxf(r2[0] / (float)D - m * m, 0.f);
    float inv = rsqrtf(var + LN_EPS);
#pragma unroll
    for (int i = 0; i < 3; i++) {
        int d = tid + i * 256;
        float v = (x[i] - m) * inv * lnw[d] + lnb[d];
        h[(size_t)token * D + d] = v;
        hb[(size_t)token * D + d] = f2b(v);
    }
}

// ---------------- residual + layernorm (fp32 out + bf16 out) ----------------
__global__ __launch_bounds__(256) void ln_residual_kernel(
    const float* __restrict__ x, const float* __restrict__ res,
    const float* __restrict__ w, const float* __restrict__ bb,
    float* __restrict__ out, unsigned short* __restrict__ outb)
{
    int token = blockIdx.x;
    int tid = threadIdx.x;
    float v[3];
    float sum = 0.f, sq = 0.f;
#pragma unroll
    for (int i = 0; i < 3; i++) {
        int d = tid + i * 256;
        float t = x[(size_t)token * D + d] + res[(size_t)token * D + d];
        v[i] = t; sum += t; sq += t * t;
    }
    __shared__ float r1[256], r2[256];
    r1[tid] = sum; r2[tid] = sq; __syncthreads();
    for (int o = 128; o > 0; o >>= 1) {
        if (tid < o) { r1[tid] += r1[tid + o]; r2[tid] += r2[tid + o]; }
        __syncthreads();
    }
    float m = r1[0] / (float)D;
    float var = fmaxf(r2[0] / (float)D - m * m, 0.f);
    float inv = rsqrtf(var + LN_EPS);
#pragma unroll
    for (int i = 0; i < 3; i++) {
        int d = tid + i * 256;
        float t = (v[i] - m) * inv * w[d] + bb[d];
        out[(size_t)token * D + d] = t;
        outb[(size_t)token * D + d] = f2b(t);
    }
}

// ---------------- transpose + fp32->bf16 convert: src K x N -> dst N x K ----------------
__global__ __launch_bounds__(256) void transpose_cvt_kernel(
    const float* __restrict__ src, unsigned short* __restrict__ dst, int K, int N)
{
    __shared__ float t[32][33];
    int tx = threadIdx.x & 31, ty = threadIdx.x >> 5;   // 32 x 8
    int kb = blockIdx.y * 32, nb = blockIdx.x * 32;
#pragma unroll
    for (int i = 0; i < 4; i++)
        t[ty + i * 8][tx] = src[(size_t)(kb + ty + i * 8) * N + nb + tx];
    __syncthreads();
#pragma unroll
    for (int i = 0; i < 4; i++)
        dst[(size_t)(nb + ty + i * 8) * K + kb + tx] = f2b(t[tx][ty + i * 8]);
}

// ---------------- bf16 MFMA GEMM, m97-style global_load_lds staging ----------------
// out = Xb(MxK) @ WTb(NxK)^T + bias; 128x128 tile, 4 waves, 4x4 16x16x32 frags
__global__ __launch_bounds__(256) void gemm_bf16_kernel(
    const unsigned short* __restrict__ Xb, const unsigned short* __restrict__ WTb,
    const float* __restrict__ bias0, const float* __restrict__ bias1,
    const float* __restrict__ bias2, int seg,
    float* __restrict__ outF, unsigned short* __restrict__ outB,
    int M, int N, int K, int act)
{
    __shared__ unsigned short As[128 * 32];   // unpadded: global_load_lds layout
    __shared__ unsigned short Bs[128 * 32];
    int tid = threadIdx.x;
    int wave = tid >> 6, lane = tid & 63;
    int wr = (wave >> 1) * 64, wc = (wave & 1) * 64;
    int row0 = blockIdx.y * 128, col0 = blockIdx.x * 128;
    int lm = lane & 15, lq = lane >> 4;
    f32x4 acc[4][4];
#pragma unroll
    for (int i = 0; i < 4; i++)
#pragma unroll
        for (int j = 0; j < 4; j++)
            acc[i][j] = (f32x4){0.f, 0.f, 0.f, 0.f};

    int srow = tid >> 2;          // 0..63
    int skq = (tid & 3) * 8;      // 0,8,16,24 shorts
    const unsigned short* gA0 = Xb + (size_t)(row0 + srow) * K + skq;
    const unsigned short* gA1 = gA0 + (size_t)64 * K;
    const unsigned short* gB0 = WTb + (size_t)(col0 + srow) * K + skq;
    const unsigned short* gB1 = gB0 + (size_t)64 * K;
    unsigned short* lA0 = As + wave * 512;
    unsigned short* lA1 = As + 2048 + wave * 512;
    unsigned short* lB0 = Bs + wave * 512;
    unsigned short* lB1 = Bs + 2048 + wave * 512;

    for (int k0 = 0; k0 < K; k0 += 32) {
        gload16(gA0 + k0, lA0);
        gload16(gA1 + k0, lA1);
        gload16(gB0 + k0, lB0);
        gload16(gB1 + k0, lB1);
        __syncthreads();
        bf16x8 af[4], bf[4];
#pragma unroll
        for (int t = 0; t < 4; t++) {
            af[t] = __builtin_bit_cast(bf16x8, *reinterpret_cast<const short8v*>(&As[(wr + t * 16 + lm) * 32 + lq * 8]));
            bf[t] = __builtin_bit_cast(bf16x8, *reinterpret_cast<const short8v*>(&Bs[(wc + t * 16 + lm) * 32 + lq * 8]));
        }
#pragma unroll
        for (int mt = 0; mt < 4; mt++)
#pragma unroll
            for (int nt = 0; nt < 4; nt++)
                acc[mt][nt] = __builtin_amdgcn_mfma_f32_16x16x32_bf16(af[mt], bf[nt], acc[mt][nt], 0, 0, 0);
        __syncthreads();
    }
#pragma unroll
    for (int mt = 0; mt < 4; mt++) {
#pragma unroll
        for (int nt = 0; nt < 4; nt++) {
            int col = col0 + wc + nt * 16 + lm;
            float bv = (col < seg) ? bias0[col] : ((col < 2 * seg) ? bias1[col - seg] : bias2[col - 2 * seg]);
#pragma unroll
            for (int r = 0; r < 4; r++) {
                int row = row0 + wr + mt * 16 + lq * 4 + r;
                float v = acc[mt][nt][r] + bv;
                if (act) v = 0.5f * v * (1.f + erff(v * 0.70710678118654752f));
                if (outF) outF[(size_t)row * N + col] = v;
                if (outB) outB[(size_t)row * N + col] = f2b(v);
            }
        }
    }
}

// ---------------- mean pool over sequence ----------------
__global__ void meanpool_kernel(const float* __restrict__ h, float* __restrict__ hbar)
{
    int d = blockIdx.x * blockDim.x + threadIdx.x;
    int b = blockIdx.y;
    float s = 0.f;
    const float* p = h + (size_t)b * SEQ * D + d;
    for (int i = 0; i < SEQ; i++) s += p[(size_t)i * D];
    hbar[b * D + d] = s * (1.0f / SEQ);
}

// ---------------- fused ctxproj(sigmoid) + metric build + GJ inverse -> bf16 ginv ----------------
__global__ __launch_bounds__(256) void metric_kernel(
    const float* __restrict__ hbar, const float* __restrict__ Wcp,
    const float* __restrict__ bcp, const float* __restrict__ Lm,
    const float* __restrict__ dg, unsigned short* __restrict__ ginvb)
{
    int b = blockIdx.x;
    int tid = threadIdx.x;
    __shared__ float cw[HD];
    __shared__ float part[256];
    __shared__ float lmod[HD][HD];
    __shared__ float AI[HD][2 * HD + 1];
    __shared__ float fvec[HD];
    __shared__ float pivinv_s;

    // ctx projection, first HD columns
    {
        int i = tid & 63, pc = tid >> 6;
        float s = 0.f;
        const float* hb = hbar + (size_t)b * D;
        for (int d = pc * 192; d < pc * 192 + 192; ++d)
            s += hb[d] * Wcp[(size_t)d * D + i];
        part[tid] = s;
        __syncthreads();
        if (tid < 64) {
            float tot = part[tid] + part[tid + 64] + part[tid + 128] + part[tid + 192] + bcp[tid];
            cw[tid] = 1.f / (1.f + __expf(-tot));
        }
        __syncthreads();
    }
    for (int idx = tid; idx < HD * HD; idx += 256) {
        int i = idx >> 6, j = idx & 63;
        lmod[i][j] = Lm[i * 64 + j] * cw[i];
    }
    __syncthreads();
    for (int idx = tid; idx < HD * HD; idx += 256) {
        int i = idx >> 6, j = idx & 63;
        float s = 0.f;
        for (int t = 0; t < HD; t++) s += lmod[i][t] * lmod[j][t];
        if (i == j) s += dg[i] + MET_EPS + 0.1f;
        AI[i][j] = s;
        AI[i][HD + j] = (i == j) ? 1.f : 0.f;
    }
    __syncthreads();
    for (int k = 0; k < HD; k++) {
        if (tid == 0) pivinv_s = 1.f / AI[k][k];
        __syncthreads();
        float pv = pivinv_s;
        if (tid < 2 * HD) AI[k][tid] *= pv;
        __syncthreads();
        if (tid < HD) fvec[tid] = AI[tid][k];
        __syncthreads();
        for (int idx = tid; idx < HD * 2 * HD; idx += 256) {
            int i = idx >> 7, j = idx & 127;
            if (i != k) AI[i][j] -= fvec[i] * AI[k][j];
        }
        __syncthreads();
    }
    for (int idx = tid; idx < HD * HD; idx += 256) {
        int i = idx >> 6, j = idx & 63;
        ginvb[((size_t)b * HD + i) * HD + j] = f2b(AI[i][HD + j]);
    }
}

// ---------------- MFMA attention with fused q@g_inv, online softmax ----------------
// block = (qtile of 64 rows, head, batch); 4 waves, wave w owns q-rows w*16..w*16+15
#define ACH 128
__global__ __launch_bounds__(256) void attn3_kernel(
    const unsigned short* __restrict__ qkvb,
    const unsigned short* __restrict__ ginvb,
    float* __restrict__ ctx)
{
    int qt = blockIdx.x, hh = blockIdx.y, b = blockIdx.z;
    int tid = threadIdx.x, wave = tid >> 6, lane = tid & 63;
    int lm = lane & 15, lq = lane >> 4;
    __shared__ unsigned short Qs[64 * 72];     // [q][d], stride 72
    __shared__ unsigned short Ks[128 * 72];    // [kpos][d]
    __shared__ unsigned short VT[64 * 136];    // [e][kpos]
    __shared__ unsigned short Ps[64 * 136];    // [q][kpos]

    const int tok0 = b * SEQ;

    // ---- Q' = Q @ Ginv (one MFMA stage, result into Qs as bf16) ----
    {
        f32x4 qacc[4];
#pragma unroll
        for (int nt = 0; nt < 4; nt++) qacc[nt] = (f32x4){0.f, 0.f, 0.f, 0.f};
        const unsigned short* gv = ginvb + (size_t)b * HD * HD;
        int qtok = tok0 + qt * 64 + wave * 16 + lm;
#pragma unroll
        for (int ks = 0; ks < 2; ks++) {
            bf16x8 aq = __builtin_bit_cast(bf16x8,
                *reinterpret_cast<const short8v*>(qkvb + (size_t)qtok * 2304 + hh * HD + ks * 32 + lq * 8));
#pragma unroll
            for (int nt = 0; nt < 4; nt++) {
                bf16x8 bg = __builtin_bit_cast(bf16x8,
                    *reinterpret_cast<const short8v*>(gv + (nt * 16 + lm) * HD + ks * 32 + lq * 8));
                qacc[nt] = __builtin_amdgcn_mfma_f32_16x16x32_bf16(aq, bg, qacc[nt], 0, 0, 0);
            }
        }
#pragma unroll
        for (int nt = 0; nt < 4; nt++)
#pragma unroll
            for (int r = 0; r < 4; r++)
                Qs[(wave * 16 + lq * 4 + r) * 72 + nt * 16 + lm] = f2b(qacc[nt][r]);
    }
    __syncthreads();

    // preload Q a-frags (fixed across chunks)
    bf16x8 aQ[2];
#pragma unroll
    for (int ks = 0; ks < 2; ks++)
        aQ[ks] = __builtin_bit_cast(bf16x8,
            *reinterpret_cast<const short8v*>(&Qs[(wave * 16 + lm) * 72 + ks * 32 + lq * 8]));

    float mrow[4], lrow[4];
    f32x4 Oacc[4];
#pragma unroll
    for (int r = 0; r < 4; r++) { mrow[r] = -1e30f; lrow[r] = 0.f; }
#pragma unroll
    for (int nt = 0; nt < 4; nt++) Oacc[nt] = (f32x4){0.f, 0.f, 0.f, 0.f};

    for (int c = 0; c < SEQ / ACH; c++) {
        __syncthreads();
        // stage K chunk rows [kpos][d]
#pragma unroll
        for (int it = 0; it < 4; it++) {
            int g = tid + it * 256;
            int kp = g >> 3, sub = (g & 7) * 8;
            *reinterpret_cast<short8v*>(&Ks[kp * 72 + sub]) =
                *reinterpret_cast<const short8v*>(qkvb + (size_t)(tok0 + c * ACH + kp) * 2304 + 768 + hh * HD + sub);
        }
        // stage V transposed [e][kpos]
        {
            int dq = (tid & 7) * 8;
            int kpb = tid >> 3;
#pragma unroll
            for (int it = 0; it < 4; it++) {
                int kpl = kpb + it * 32;
                short8v vv = *reinterpret_cast<const short8v*>(
                    qkvb + (size_t)(tok0 + c * ACH + kpl) * 2304 + 1536 + hh * HD + dq);
                const unsigned short* vel = (const unsigned short*)&vv;
#pragma unroll
                for (int j = 0; j < 8; j++)
                    VT[(dq + j) * 136 + kpl] = vel[j];
            }
        }
        __syncthreads();

        // QK^T: S tile 16(rows of this wave) x 128
        f32x4 sacc[8];
#pragma unroll
        for (int nt = 0; nt < 8; nt++) sacc[nt] = (f32x4){0.f, 0.f, 0.f, 0.f};
#pragma unroll
        for (int ks = 0; ks < 2; ks++)
#pragma unroll
            for (int nt = 0; nt < 8; nt++) {
                bf16x8 bk = __builtin_bit_cast(bf16x8,
                    *reinterpret_cast<const short8v*>(&Ks[(nt * 16 + lm) * 72 + ks * 32 + lq * 8]));
                sacc[nt] = __builtin_amdgcn_mfma_f32_16x16x32_bf16(aQ[ks], bk, sacc[nt], 0, 0, 0);
            }
        // online softmax (rows = lq*4 + r of this wave's 16-row tile)
        float mnew[4], alpha[4], rs[4];
#pragma unroll
        for (int nt = 0; nt < 8; nt++)
#pragma unroll
            for (int r = 0; r < 4; r++) sacc[nt][r] *= 0.125f;
#pragma unroll
        for (int r = 0; r < 4; r++) {
            float mx = -1e30f;
#pragma unroll
            for (int nt = 0; nt < 8; nt++) mx = fmaxf(mx, sacc[nt][r]);
            mx = fmaxf(mx, __shfl_xor(mx, 1));
            mx = fmaxf(mx, __shfl_xor(mx, 2));
            mx = fmaxf(mx, __shfl_xor(mx, 4));
            mx = fmaxf(mx, __shfl_xor(mx, 8));
            mnew[r] = fmaxf(mrow[r], mx);
            alpha[r] = __expf(mrow[r] - mnew[r]);
            mrow[r] = mnew[r];
            rs[r] = 0.f;
        }
#pragma unroll
        for (int nt = 0; nt < 8; nt++)
#pragma unroll
            for (int r = 0; r < 4; r++) {
                float p = __expf(sacc[nt][r] - mrow[r]);
                sacc[nt][r] = p;
                rs[r] += p;
            }
#pragma unroll
        for (int r = 0; r < 4; r++) {
            rs[r] += __shfl_xor(rs[r], 1);
            rs[r] += __shfl_xor(rs[r], 2);
            rs[r] += __shfl_xor(rs[r], 4);
            rs[r] += __shfl_xor(rs[r], 8);
            lrow[r] = lrow[r] * alpha[r] + rs[r];
        }
#pragma unroll
        for (int nt = 0; nt < 4; nt++)
#pragma unroll
            for (int r = 0; r < 4; r++) Oacc[nt][r] *= alpha[r];
        // P -> LDS (A-layout rows)
#pragma unroll
        for (int nt = 0; nt < 8; nt++)
#pragma unroll
            for (int r = 0; r < 4; r++)
                Ps[(wave * 16 + lq * 4 + r) * 136 + nt * 16 + lm] = f2b(sacc[nt][r]);
        __syncthreads();
        // PV
#pragma unroll
        for (int ks = 0; ks < 4; ks++) {
            bf16x8 ap = __builtin_bit_cast(bf16x8,
                *reinterpret_cast<const short8v*>(&Ps[(wave * 16 + lm) * 136 + ks * 32 + lq * 8]));
#pragma unroll
            for (int nt = 0; nt < 4; nt++) {
                bf16x8 bv = __builtin_bit_cast(bf16x8,
                    *reinterpret_cast<const short8v*>(&VT[(nt * 16 + lm) * 136 + ks * 32 + lq * 8]));
                Oacc[nt] = __builtin_amdgcn_mfma_f32_16x16x32_bf16(ap, bv, Oacc[nt], 0, 0, 0);
            }
        }
    }
    // epilogue
#pragma unroll
    for (int r = 0; r < 4; r++) {
        int row = qt * 64 + wave * 16 + lq * 4 + r;
        float inv = 1.f / lrow[r];
#pragma unroll
        for (int nt = 0; nt < 4; nt++)
            ctx[(size_t)(tok0 + row) * D + hh * HD + nt * 16 + lm] = Oacc[nt][r] * inv;
    }
}

// ---------------- host ----------------
extern "C" void kernel_launch(void* const* d_in, const int* in_sizes, int n_in,
                              void* d_out, int out_size, void* d_ws, size_t ws_size,
                              hipStream_t stream)
{
    (void)in_sizes; (void)n_in; (void)out_size; (void)ws_size;
    const int*   input_ids  = (const int*)d_in[0];
    const int*   token_type = (const int*)d_in[1];
    const float* word_emb   = (const float*)d_in[2];
    const float* pos_emb    = (const float*)d_in[3];
    const float* type_emb   = (const float*)d_in[4];
    const float* ln_emb_w   = (const float*)d_in[5];
    const float* ln_emb_b   = (const float*)d_in[6];
    const float* Wq = (const float*)d_in[7];
    const float* bq = (const float*)d_in[8];
    const float* Wk = (const float*)d_in[9];
    const float* bk = (const float*)d_in[10];
    const float* Wv = (const float*)d_in[11];
    const float* bv = (const float*)d_in[12];
    const float* Lm = (const float*)d_in[13];
    const float* dg = (const float*)d_in[14];
    const float* Wcp = (const float*)d_in[15];
    const float* bcp = (const float*)d_in[16];
    const float* Wi = (const float*)d_in[17];
    const float* bi = (const float*)d_in[18];
    const float* Wo = (const float*)d_in[19];
    const float* bo = (const float*)d_in[20];
    const float* ln1w = (const float*)d_in[21];
    const float* ln1b = (const float*)d_in[22];
    const float* ln2w = (const float*)d_in[23];
    const float* ln2b = (const float*)d_in[24];

    float* h = (float*)d_out;

    char* wsb = (char*)d_ws;
    size_t off = 0;
    auto alloc = [&](size_t bytes) { void* p = wsb + off; off += (bytes + 255) & ~(size_t)255; return p; };
    unsigned short* qkvb = (unsigned short*)alloc((size_t)BT * 2304 * 2);
    float*          ctx  = (float*)alloc((size_t)BT * D * 4);
    float*          a    = (float*)alloc((size_t)BT * D * 4);
    unsigned short* hb   = (unsigned short*)alloc((size_t)BT * D * 2);
    unsigned short* fb   = (unsigned short*)alloc((size_t)BT * FF * 2);
    unsigned short* WqkvT= (unsigned short*)alloc((size_t)2304 * 768 * 2);
    unsigned short* WiT  = (unsigned short*)alloc((size_t)3072 * 768 * 2);
    unsigned short* WoT  = (unsigned short*)alloc((size_t)768 * 3072 * 2);
    float*          hbar = (float*)alloc((size_t)BATCH * D * 4);
    unsigned short* ginvb= (unsigned short*)alloc((size_t)BATCH * HD * HD * 2);
    unsigned short* ab = hb;
    float* obuf = ctx;

    embed_ln_kernel<<<BT, 256, 0, stream>>>(input_ids, token_type, word_emb, pos_emb,
                                            type_emb, ln_emb_w, ln_emb_b, h, hb);

    for (int l = 0; l < NL; ++l) {
        const float* Wq_l = Wq + (size_t)l * D * D;
        const float* bq_l = bq + (size_t)l * D;
        const float* Wk_l = Wk + (size_t)l * D * D;
        const float* bk_l = bk + (size_t)l * D;
        const float* Wv_l = Wv + (size_t)l * D * D;
        const float* bv_l = bv + (size_t)l * D;
        const float* Lm_l = Lm + (size_t)l * D * 64;
        const float* dg_l = dg + (size_t)l * D;
        const float* Wcp_l = Wcp + (size_t)l * D * D;
        const float* bcp_l = bcp + (size_t)l * D;
        const float* Wi_l = Wi + (size_t)l * D * FF;
        const float* bi_l = bi + (size_t)l * FF;
        const float* Wo_l = Wo + (size_t)l * FF * D;
        const float* bo_l = bo + (size_t)l * D;
        const float* ln1w_l = ln1w + (size_t)l * D;
        const float* ln1b_l = ln1b + (size_t)l * D;
        const float* ln2w_l = ln2w + (size_t)l * D;
        const float* ln2b_l = ln2b + (size_t)l * D;

        transpose_cvt_kernel<<<dim3(24, 24), 256, 0, stream>>>(Wq_l, WqkvT,                 768, 768);
        transpose_cvt_kernel<<<dim3(24, 24), 256, 0, stream>>>(Wk_l, WqkvT + 768 * 768,     768, 768);
        transpose_cvt_kernel<<<dim3(24, 24), 256, 0, stream>>>(Wv_l, WqkvT + 2 * 768 * 768, 768, 768);
        transpose_cvt_kernel<<<dim3(96, 24), 256, 0, stream>>>(Wi_l, WiT, 768, 3072);
        transpose_cvt_kernel<<<dim3(24, 96), 256, 0, stream>>>(Wo_l, WoT, 3072, 768);

        gemm_bf16_kernel<<<dim3(2304 / 128, BT / 128), 256, 0, stream>>>(
            hb, WqkvT, bq_l, bk_l, bv_l, 768, nullptr, qkvb, BT, 2304, 768, 0);

        meanpool_kernel<<<dim3(D / 256, BATCH), 256, 0, stream>>>(h, hbar);
        metric_kernel<<<BATCH, 256, 0, stream>>>(hbar, Wcp_l, bcp_l, Lm_l, dg_l, ginvb);

        attn3_kernel<<<dim3(SEQ / 64, NH, BATCH), 256, 0, stream>>>(qkvb, ginvb, ctx);

        ln_residual_kernel<<<BT, 256, 0, stream>>>(ctx, h, ln1w_l, ln1b_l, a, ab);

        gemm_bf16_kernel<<<dim3(FF / 128, BT / 128), 256, 0, stream>>>(
            ab, WiT, bi_l, bi_l, bi_l, FF, nullptr, fb, BT, FF, 768, 1);
        gemm_bf16_kernel<<<dim3(D / 128, BT / 128), 256, 0, stream>>>(
            fb, WoT, bo_l, bo_l, bo_l, D, obuf, nullptr, BT, D, FF, 0);

        ln_residual_kernel<<<BT, 256, 0, stream>>>(obuf, a, ln2w_l, ln2b_l, h, hb);
    }
}